// Round 1
// baseline (183.985 us; speedup 1.0000x reference)
//
#include <hip/hip_runtime.h>
#include <hip/hip_bf16.h>

typedef __bf16 bf16;
typedef __bf16 bf16x2 __attribute__((ext_vector_type(2)));
typedef __bf16 bf16x8 __attribute__((ext_vector_type(8)));
typedef float f32x4 __attribute__((ext_vector_type(4)));
typedef int i32x4 __attribute__((ext_vector_type(4)));

#define B_ 8
#define N_ 1024
#define C_ 256
#define H_ 8
#define C3_ 768
#define SCALE 0.17677669529663689f  // 1/sqrt(32), pre-folded into q
#define FMAX 16.0f                  // fixed softmax max, pre-folded into btl

// ws layout:
//   Wq_tiled [8 kt][12 nt][64 n][32 k]   393216 B  @ 0
//   Wp_tiled [8 kt][256 n][32 k]         131072 B  @ 393216
//   q  [8192][256] (pre-scaled by SCALE) 4 MiB     @ 524288
//   kT [b][h][1024 n][32 d]              4 MiB     @ 4718592
//   vT [b][c=h*32+d][1024 n']            4 MiB     @ 8912896
// perm(n within 32): n' = (n&~31) | 2*(n&15) | ((n>>4)&1)

// ---------------------------------------------------------------------------
// prep: transpose + convert weights into tiled bf16 layouts (one-off, tiny).
// ---------------------------------------------------------------------------
__global__ __launch_bounds__(256) void prep(
    const float* __restrict__ Wqkv, const float* __restrict__ Wproj,
    bf16* __restrict__ Wq_tiled, bf16* __restrict__ Wp_tiled)
{
  int bb = blockIdx.x;
  int o = bb * 256 + threadIdx.x;
  if (bb < 768) {
    int kk = o & 31;
    int idx = o >> 5;
    int nr = idx & 63;
    int qq = idx >> 6;            // kt*12 + nt
    int nt = qq % 12, kt = qq / 12;
    int n = nt * 64 + nr, k = kt * 32 + kk;
    Wq_tiled[o] = (bf16)Wqkv[k * C3_ + n];
  } else {
    int p = o - 768 * 256;
    int kk = p & 31;
    int n = (p >> 5) & 255;
    int kt = p >> 13;
    int k = kt * 32 + kk;
    Wp_tiled[p] = (bf16)Wproj[k * C_ + n];
  }
}

// ---------------------------------------------------------------------------
// QKV projection, 128x128 block tile (m93-class): 4 waves, each 64x64 via
// 4x4 f32x4 accumulators -> 16 MFMA per 8 ds_read_b128 per k-step.
// ---------------------------------------------------------------------------
__global__ __launch_bounds__(256) void gemm_qkv(
    const float* __restrict__ A, const bf16* __restrict__ Wq_tiled,
    bf16* __restrict__ q, bf16* __restrict__ kT, bf16* __restrict__ vT)
{
  __shared__ bf16 As[128][40];
  __shared__ bf16 Bts[128][40];   // Bts[n][k]
  __shared__ bf16 Vls[64][136];   // v-epilogue transpose buffer (64ch x 128n)

  int tid = threadIdx.x;
  int wave = tid >> 6, lane = tid & 63, quad = lane >> 4, l16 = lane & 15;
  int m0 = blockIdx.x * 128, n0 = blockIdx.y * 128;
  int msub = (wave & 1) * 64, nsub = (wave >> 1) * 64;

  f32x4 acc[4][4] = {};

  int arow = tid >> 1, akc = (tid & 1) * 16;
  const float* aptr = A + (long)(m0 + arow) * C_ + akc;   // + k0
  int bn = tid >> 1, bkc = (tid & 1) * 16;
  const bf16* bptr = Wq_tiled +
      ((long)(blockIdx.y * 2 + (bn >> 6)) * 2048 + (bn & 63) * 32 + bkc);

  float4 a0 = *reinterpret_cast<const float4*>(aptr);
  float4 a1 = *reinterpret_cast<const float4*>(aptr + 4);
  float4 a2 = *reinterpret_cast<const float4*>(aptr + 8);
  float4 a3 = *reinterpret_cast<const float4*>(aptr + 12);
  i32x4 bv0 = *reinterpret_cast<const i32x4*>(bptr);
  i32x4 bv1 = *reinterpret_cast<const i32x4*>(bptr + 8);

  for (int kt = 0; kt < 8; ++kt) {
    __syncthreads();
    {
      bf16 at[16] = {(bf16)a0.x, (bf16)a0.y, (bf16)a0.z, (bf16)a0.w,
                     (bf16)a1.x, (bf16)a1.y, (bf16)a1.z, (bf16)a1.w,
                     (bf16)a2.x, (bf16)a2.y, (bf16)a2.z, (bf16)a2.w,
                     (bf16)a3.x, (bf16)a3.y, (bf16)a3.z, (bf16)a3.w};
      *reinterpret_cast<bf16x8*>(&As[arow][akc]) = *reinterpret_cast<bf16x8*>(at);
      *reinterpret_cast<bf16x8*>(&As[arow][akc + 8]) = *reinterpret_cast<bf16x8*>(at + 8);
      *reinterpret_cast<i32x4*>(&Bts[bn][bkc]) = bv0;
      *reinterpret_cast<i32x4*>(&Bts[bn][bkc + 8]) = bv1;
    }
    __syncthreads();

    if (kt < 7) {
      int kn = (kt + 1) * 32;
      a0 = *reinterpret_cast<const float4*>(aptr + kn);
      a1 = *reinterpret_cast<const float4*>(aptr + kn + 4);
      a2 = *reinterpret_cast<const float4*>(aptr + kn + 8);
      a3 = *reinterpret_cast<const float4*>(aptr + kn + 12);
      bv0 = *reinterpret_cast<const i32x4*>(bptr + (long)(kt + 1) * 24576);
      bv1 = *reinterpret_cast<const i32x4*>(bptr + (long)(kt + 1) * 24576 + 8);
    }

    bf16x8 af[4], bfr[4];
#pragma unroll
    for (int mi = 0; mi < 4; ++mi)
      af[mi] = *reinterpret_cast<const bf16x8*>(&As[msub + mi * 16 + l16][quad * 8]);
#pragma unroll
    for (int ni = 0; ni < 4; ++ni)
      bfr[ni] = *reinterpret_cast<const bf16x8*>(&Bts[nsub + ni * 16 + l16][quad * 8]);
#pragma unroll
    for (int mi = 0; mi < 4; ++mi)
#pragma unroll
      for (int ni = 0; ni < 4; ++ni)
        acc[mi][ni] = __builtin_amdgcn_mfma_f32_16x16x32_bf16(af[mi], bfr[ni], acc[mi][ni], 0, 0, 0);
  }

  if (n0 < 256) {
#pragma unroll
    for (int mi = 0; mi < 4; ++mi)
#pragma unroll
      for (int ni = 0; ni < 4; ++ni)
#pragma unroll
        for (int r = 0; r < 4; ++r) {
          int row = m0 + msub + mi * 16 + quad * 4 + r;
          int col = n0 + nsub + ni * 16 + l16;
          q[(long)row * 256 + col] = (bf16)(acc[mi][ni][r] * SCALE);
        }
  } else if (n0 < 512) {
#pragma unroll
    for (int mi = 0; mi < 4; ++mi)
#pragma unroll
      for (int ni = 0; ni < 4; ++ni)
#pragma unroll
        for (int r = 0; r < 4; ++r) {
          int row = m0 + msub + mi * 16 + quad * 4 + r;
          int c = n0 + nsub + ni * 16 + l16 - 256;
          int b = row >> 10, n = row & 1023;
          int h = c >> 5, d = c & 31;
          kT[(((long)(b * H_ + h)) * N_ + n) * 32 + d] = (bf16)acc[mi][ni][r];
        }
  } else {
    int b = m0 >> 10;
#pragma unroll
    for (int ch = 0; ch < 2; ++ch) {
      __syncthreads();
      if ((nsub >> 6) == ch) {
#pragma unroll
        for (int mi = 0; mi < 4; ++mi)
#pragma unroll
          for (int ni = 0; ni < 4; ++ni)
#pragma unroll
            for (int r = 0; r < 4; ++r) {
              int cc = ni * 16 + l16;                  // 0..63 within half
              int nn = msub + mi * 16 + quad * 4 + r;  // 0..127
              int np = (nn & 96) | (2 * (nn & 15)) | ((nn >> 4) & 1);
              Vls[cc][np] = (bf16)acc[mi][ni][r];
            }
      }
      __syncthreads();
      int cc = tid >> 2, nseg = (tid & 3) * 32;
      long base = ((long)(b * C_ + (n0 - 512) + ch * 64 + cc)) * N_ + (m0 & 1023) + nseg;
#pragma unroll
      for (int j = 0; j < 4; ++j)
        *reinterpret_cast<i32x4*>(vT + base + j * 8) =
            *reinterpret_cast<const i32x4*>(&Vls[cc][nseg + j * 8]);
    }
  }
}

// ---------------------------------------------------------------------------
// Flash attention + fused output projection — BARRIER-FREE j-loop.
// One wave per head, 16-row i-tile. V + rel are read DIRECTLY from global
// (vT's j-permutation matches the P write layout, so the former Vs LDS read
// is just a coalesced global load). No __syncthreads in the j-loop: waves
// drift independently, hiding each other's stalls. K/V double-buffered
// (distance 2 steps, L2-hit), rel quad-buffered (distance 4 steps > HBM
// miss latency). XCD swizzle: each XCD owns one batch b -> kT/vT/q slices
// are L2-resident per XCD.
// ---------------------------------------------------------------------------
__global__ __launch_bounds__(512, 4) void flash_attn(
    const bf16* __restrict__ q, const bf16* __restrict__ kT,
    const bf16* __restrict__ vT, const int* __restrict__ rel,
    const int* __restrict__ rel_len, const float* __restrict__ btab,
    const bf16* __restrict__ Wp_tiled, const float* __restrict__ bias,
    float* __restrict__ out)
{
  __shared__ bf16 Pls[H_][16 * 40]; // wave-private P scratch
  __shared__ float btl[H_][16];     // bias + mask - FMAX
  __shared__ bf16 attL[16][264];    // normalized att rows (all 256 channels)

  int tid = threadIdx.x;
  int h = tid >> 6, lane = tid & 63, quad = lane >> 4, l16 = lane & 15;

  // bijective XCD swizzle (512 blocks = 8 XCDs x 64): XCD k -> batch k.
  int wg = blockIdx.y * 64 + blockIdx.x;
  int swz = (wg & 7) * 64 + (wg >> 3);
  int b = swz >> 6, i0 = (swz & 63) * 16;
  long bN = (long)b * N_;

  int mask_len = (int)((float)rel_len[b] * 0.5f);
  if (tid < 80) {
    int t = tid >> 3, hh = tid & 7;
    btl[hh][t] = btab[t * H_ + hh] + (t > mask_len ? -100.f : 0.f) - FMAX;
  }
  __syncthreads();  // btl ready (only barrier before the tail)

  bf16x8 qf = *reinterpret_cast<const bf16x8*>(
      q + (bN + i0 + l16) * 256 + h * 32 + quad * 8);

  const bf16* kb_ = kT + ((long)(b * H_ + h)) * N_ * 32 + quad * 8;   // + (j+row)*32
  const bf16* vb_ = vT + ((long)b * C_ + h * 32 + l16) * N_ + quad * 8; // + j (+16*N_ row)
  const int*  rb_ = rel + (bN + i0 + quad * 4) * N_ + l16;            // + r*N_ + j (+16)

#define W_(J) ((J) < N_ ? (J) : 0)

#define LDK(K0, K1, V0, V1, J) do {                                          \
    K0 = *reinterpret_cast<const bf16x8*>(kb_ + (long)((J) + l16) * 32);     \
    K1 = *reinterpret_cast<const bf16x8*>(kb_ + (long)((J) + 16 + l16) * 32);\
    V0 = *reinterpret_cast<const bf16x8*>(vb_ + (J));                        \
    V1 = *reinterpret_cast<const bf16x8*>(vb_ + 16 * N_ + (J));              \
  } while (0)

#define LDR(RV, J) do {                                                      \
    _Pragma("unroll")                                                        \
    for (int r = 0; r < 4; ++r) {                                            \
      RV[2 * r]     = rb_[r * N_ + (J)];                                     \
      RV[2 * r + 1] = rb_[r * N_ + (J) + 16];                                \
    }                                                                        \
  } while (0)

#define COMP(K0, K1, V0, V1, RV) do {                                        \
    f32x4 z = {};                                                            \
    f32x4 s0 = __builtin_amdgcn_mfma_f32_16x16x32_bf16(qf, K0, z, 0, 0, 0);  \
    f32x4 s1 = __builtin_amdgcn_mfma_f32_16x16x32_bf16(qf, K1, z, 0, 0, 0);  \
    _Pragma("unroll")                                                        \
    for (int r = 0; r < 4; ++r) {                                            \
      float p0 = __expf(s0[r] + btl[h][RV[2 * r]]);                          \
      float p1 = __expf(s1[r] + btl[h][RV[2 * r + 1]]);                      \
      l_part[r] += p0 + p1;                                                  \
      bf16x2 pp = {(bf16)p0, (bf16)p1}; /* cols 2*l16, 2*l16+1 (j-perm) */   \
      *reinterpret_cast<bf16x2*>(&Pls[h][(quad * 4 + r) * 40 + l16 * 2]) = pp;\
    }                                                                        \
    asm volatile("s_waitcnt lgkmcnt(0)" ::: "memory");                       \
    bf16x8 pf = *reinterpret_cast<const bf16x8*>(&Pls[h][l16 * 40 + quad * 8]);\
    oacc[0] = __builtin_amdgcn_mfma_f32_16x16x32_bf16(pf, V0, oacc[0], 0, 0, 0);\
    oacc[1] = __builtin_amdgcn_mfma_f32_16x16x32_bf16(pf, V1, oacc[1], 0, 0, 0);\
  } while (0)

  f32x4 oacc[2] = {};
  float l_part[4] = {0.f, 0.f, 0.f, 0.f};

  bf16x8 ka0, ka1, vA0, vA1, kb0, kb1, vB0, vB1;
  int r0[8], r1[8], r2[8], r3[8];

  LDK(ka0, ka1, vA0, vA1, 0);
  LDK(kb0, kb1, vB0, vB1, 32);
  LDR(r0, 0); LDR(r1, 32); LDR(r2, 64); LDR(r3, 96);

#pragma unroll 1
  for (int j0 = 0; j0 < N_; j0 += 128) {
    COMP(ka0, ka1, vA0, vA1, r0); LDK(ka0, ka1, vA0, vA1, W_(j0 + 64));  LDR(r0, W_(j0 + 128));
    COMP(kb0, kb1, vB0, vB1, r1); LDK(kb0, kb1, vB0, vB1, W_(j0 + 96));  LDR(r1, W_(j0 + 160));
    COMP(ka0, ka1, vA0, vA1, r2); LDK(ka0, ka1, vA0, vA1, W_(j0 + 128)); LDR(r2, W_(j0 + 192));
    COMP(kb0, kb1, vB0, vB1, r3); LDK(kb0, kb1, vB0, vB1, W_(j0 + 160)); LDR(r3, W_(j0 + 224));
  }

  // normalize -> attL (bf16, all channels of this block's 16 rows)
#pragma unroll
  for (int r = 0; r < 4; ++r) {
    float l = l_part[r];
#pragma unroll
    for (int m = 1; m < 16; m <<= 1) l += __shfl_xor(l, m);
    float inv = 1.f / l;
    attL[quad * 4 + r][h * 32 + l16] = (bf16)(oacc[0][r] * inv);
    attL[quad * 4 + r][h * 32 + 16 + l16] = (bf16)(oacc[1][r] * inv);
  }
  __syncthreads();

  // fused projection: wave h computes out[16 rows][h*32 .. h*32+31]
  f32x4 pacc[2] = {};
  const bf16* wp = Wp_tiled + ((h * 32 + l16) * 32 + quad * 8);  // + kt*8192, +512 for ni=1
#pragma unroll
  for (int kt = 0; kt < 8; ++kt) {
    bf16x8 afr = *reinterpret_cast<const bf16x8*>(&attL[l16][kt * 32 + quad * 8]);
    bf16x8 b0 = *reinterpret_cast<const bf16x8*>(wp + kt * 8192);
    bf16x8 b1 = *reinterpret_cast<const bf16x8*>(wp + kt * 8192 + 512);
    pacc[0] = __builtin_amdgcn_mfma_f32_16x16x32_bf16(afr, b0, pacc[0], 0, 0, 0);
    pacc[1] = __builtin_amdgcn_mfma_f32_16x16x32_bf16(afr, b1, pacc[1], 0, 0, 0);
  }
  float bi0 = bias[h * 32 + l16];
  float bi1 = bias[h * 32 + 16 + l16];
#pragma unroll
  for (int r = 0; r < 4; ++r) {
    long rowoff = (bN + i0 + quad * 4 + r) * C_ + h * 32;
    out[rowoff + l16] = pacc[0][r] + bi0;
    out[rowoff + 16 + l16] = pacc[1][r] + bi1;
  }
#undef W_
#undef LDK
#undef LDR
#undef COMP
}

// ---------------------------------------------------------------------------
extern "C" void kernel_launch(void* const* d_in, const int* in_sizes, int n_in,
                              void* d_out, int out_size, void* d_ws, size_t ws_size,
                              hipStream_t stream) {
  const float* X     = (const float*)d_in[0];   // att_embedding [8,1024,256] fp32
  const int*   rel   = (const int*)d_in[1];     // relation_position [8,1024,1024]
  const int*   rlen  = (const int*)d_in[2];     // rel_len [8]
  const float* Wqkv  = (const float*)d_in[3];   // [256,768] fp32
  const float* Wproj = (const float*)d_in[4];   // [256,256] fp32
  const float* bproj = (const float*)d_in[5];   // [256] fp32
  const float* btab  = (const float*)d_in[6];   // [10,8] fp32
  float* out = (float*)d_out;                   // [8,1024,256] fp32

  char* ws = (char*)d_ws;
  bf16* Wq_tiled = (bf16*)ws;                            // 393216 B
  bf16* Wp_tiled = (bf16*)(ws + 393216);                 // 131072 B
  bf16* q  = (bf16*)(ws + 524288);                       // 4 MiB
  bf16* kT = (bf16*)(ws + 524288 + 4194304);             // 4 MiB
  bf16* vT = (bf16*)(ws + 524288 + 2 * 4194304);         // 4 MiB

  prep<<<dim3(1024), 256, 0, stream>>>(Wqkv, Wproj, Wq_tiled, Wp_tiled);
  gemm_qkv<<<dim3(8192 / 128, C3_ / 128), 256, 0, stream>>>(X, Wq_tiled, q, kT, vT);
  flash_attn<<<dim3(N_ / 16, B_), 512, 0, stream>>>(
      q, kT, vT, rel, rlen, btab, Wp_tiled, bproj, out);
}

// Round 2
// 160.496 us; speedup vs baseline: 1.1464x; 1.1464x over previous
//
#include <hip/hip_runtime.h>
#include <hip/hip_bf16.h>

typedef __bf16 bf16;
typedef __bf16 bf16x2 __attribute__((ext_vector_type(2)));
typedef __bf16 bf16x8 __attribute__((ext_vector_type(8)));
typedef float f32x4 __attribute__((ext_vector_type(4)));
typedef int i32x4 __attribute__((ext_vector_type(4)));

#define B_ 8
#define N_ 1024
#define C_ 256
#define H_ 8
#define C3_ 768
#define SCALE 0.17677669529663689f  // 1/sqrt(32), pre-folded into q
#define FMAX 16.0f                  // fixed softmax max, pre-folded into btl

// ws layout:
//   Wq_tiled [8 kt][12 nt][64 n][32 k]   393216 B  @ 0
//   Wp_tiled [8 kt][256 n][32 k]         131072 B  @ 393216
//   q  [8192][256] (pre-scaled by SCALE) 4 MiB     @ 524288
//   kT [b][h][1024 n][32 d]              4 MiB     @ 4718592
//   vT [b][c=h*32+d][1024 n']            4 MiB     @ 8912896
// perm(n within 32): n' = (n&~31) | 2*(n&15) | ((n>>4)&1)

// ---------------------------------------------------------------------------
// prep: transpose + convert weights into tiled bf16 layouts (one-off, tiny).
// ---------------------------------------------------------------------------
__global__ __launch_bounds__(256) void prep(
    const float* __restrict__ Wqkv, const float* __restrict__ Wproj,
    bf16* __restrict__ Wq_tiled, bf16* __restrict__ Wp_tiled)
{
  int bb = blockIdx.x;
  int o = bb * 256 + threadIdx.x;
  if (bb < 768) {
    int kk = o & 31;
    int idx = o >> 5;
    int nr = idx & 63;
    int qq = idx >> 6;            // kt*12 + nt
    int nt = qq % 12, kt = qq / 12;
    int n = nt * 64 + nr, k = kt * 32 + kk;
    Wq_tiled[o] = (bf16)Wqkv[k * C3_ + n];
  } else {
    int p = o - 768 * 256;
    int kk = p & 31;
    int n = (p >> 5) & 255;
    int kt = p >> 13;
    int k = kt * 32 + kk;
    Wp_tiled[p] = (bf16)Wproj[k * C_ + n];
  }
}

// ---------------------------------------------------------------------------
// QKV projection, 128x128 block tile (m93-class): 4 waves, each 64x64 via
// 4x4 f32x4 accumulators -> 16 MFMA per 8 ds_read_b128 per k-step.
// ---------------------------------------------------------------------------
__global__ __launch_bounds__(256) void gemm_qkv(
    const float* __restrict__ A, const bf16* __restrict__ Wq_tiled,
    bf16* __restrict__ q, bf16* __restrict__ kT, bf16* __restrict__ vT)
{
  __shared__ bf16 As[128][40];
  __shared__ bf16 Bts[128][40];   // Bts[n][k]
  __shared__ bf16 Vls[64][136];   // v-epilogue transpose buffer (64ch x 128n)

  int tid = threadIdx.x;
  int wave = tid >> 6, lane = tid & 63, quad = lane >> 4, l16 = lane & 15;
  int m0 = blockIdx.x * 128, n0 = blockIdx.y * 128;
  int msub = (wave & 1) * 64, nsub = (wave >> 1) * 64;

  f32x4 acc[4][4] = {};

  int arow = tid >> 1, akc = (tid & 1) * 16;
  const float* aptr = A + (long)(m0 + arow) * C_ + akc;   // + k0
  int bn = tid >> 1, bkc = (tid & 1) * 16;
  const bf16* bptr = Wq_tiled +
      ((long)(blockIdx.y * 2 + (bn >> 6)) * 2048 + (bn & 63) * 32 + bkc);

  float4 a0 = *reinterpret_cast<const float4*>(aptr);
  float4 a1 = *reinterpret_cast<const float4*>(aptr + 4);
  float4 a2 = *reinterpret_cast<const float4*>(aptr + 8);
  float4 a3 = *reinterpret_cast<const float4*>(aptr + 12);
  i32x4 bv0 = *reinterpret_cast<const i32x4*>(bptr);
  i32x4 bv1 = *reinterpret_cast<const i32x4*>(bptr + 8);

  for (int kt = 0; kt < 8; ++kt) {
    __syncthreads();
    {
      bf16 at[16] = {(bf16)a0.x, (bf16)a0.y, (bf16)a0.z, (bf16)a0.w,
                     (bf16)a1.x, (bf16)a1.y, (bf16)a1.z, (bf16)a1.w,
                     (bf16)a2.x, (bf16)a2.y, (bf16)a2.z, (bf16)a2.w,
                     (bf16)a3.x, (bf16)a3.y, (bf16)a3.z, (bf16)a3.w};
      *reinterpret_cast<bf16x8*>(&As[arow][akc]) = *reinterpret_cast<bf16x8*>(at);
      *reinterpret_cast<bf16x8*>(&As[arow][akc + 8]) = *reinterpret_cast<bf16x8*>(at + 8);
      *reinterpret_cast<i32x4*>(&Bts[bn][bkc]) = bv0;
      *reinterpret_cast<i32x4*>(&Bts[bn][bkc + 8]) = bv1;
    }
    __syncthreads();

    if (kt < 7) {
      int kn = (kt + 1) * 32;
      a0 = *reinterpret_cast<const float4*>(aptr + kn);
      a1 = *reinterpret_cast<const float4*>(aptr + kn + 4);
      a2 = *reinterpret_cast<const float4*>(aptr + kn + 8);
      a3 = *reinterpret_cast<const float4*>(aptr + kn + 12);
      bv0 = *reinterpret_cast<const i32x4*>(bptr + (long)(kt + 1) * 24576);
      bv1 = *reinterpret_cast<const i32x4*>(bptr + (long)(kt + 1) * 24576 + 8);
    }

    bf16x8 af[4], bfr[4];
#pragma unroll
    for (int mi = 0; mi < 4; ++mi)
      af[mi] = *reinterpret_cast<const bf16x8*>(&As[msub + mi * 16 + l16][quad * 8]);
#pragma unroll
    for (int ni = 0; ni < 4; ++ni)
      bfr[ni] = *reinterpret_cast<const bf16x8*>(&Bts[nsub + ni * 16 + l16][quad * 8]);
#pragma unroll
    for (int mi = 0; mi < 4; ++mi)
#pragma unroll
      for (int ni = 0; ni < 4; ++ni)
        acc[mi][ni] = __builtin_amdgcn_mfma_f32_16x16x32_bf16(af[mi], bfr[ni], acc[mi][ni], 0, 0, 0);
  }

  if (n0 < 256) {
#pragma unroll
    for (int mi = 0; mi < 4; ++mi)
#pragma unroll
      for (int ni = 0; ni < 4; ++ni)
#pragma unroll
        for (int r = 0; r < 4; ++r) {
          int row = m0 + msub + mi * 16 + quad * 4 + r;
          int col = n0 + nsub + ni * 16 + l16;
          q[(long)row * 256 + col] = (bf16)(acc[mi][ni][r] * SCALE);
        }
  } else if (n0 < 512) {
#pragma unroll
    for (int mi = 0; mi < 4; ++mi)
#pragma unroll
      for (int ni = 0; ni < 4; ++ni)
#pragma unroll
        for (int r = 0; r < 4; ++r) {
          int row = m0 + msub + mi * 16 + quad * 4 + r;
          int c = n0 + nsub + ni * 16 + l16 - 256;
          int b = row >> 10, n = row & 1023;
          int h = c >> 5, d = c & 31;
          kT[(((long)(b * H_ + h)) * N_ + n) * 32 + d] = (bf16)acc[mi][ni][r];
        }
  } else {
    int b = m0 >> 10;
#pragma unroll
    for (int ch = 0; ch < 2; ++ch) {
      __syncthreads();
      if ((nsub >> 6) == ch) {
#pragma unroll
        for (int mi = 0; mi < 4; ++mi)
#pragma unroll
          for (int ni = 0; ni < 4; ++ni)
#pragma unroll
            for (int r = 0; r < 4; ++r) {
              int cc = ni * 16 + l16;                  // 0..63 within half
              int nn = msub + mi * 16 + quad * 4 + r;  // 0..127
              int np = (nn & 96) | (2 * (nn & 15)) | ((nn >> 4) & 1);
              Vls[cc][np] = (bf16)acc[mi][ni][r];
            }
      }
      __syncthreads();
      int cc = tid >> 2, nseg = (tid & 3) * 32;
      long base = ((long)(b * C_ + (n0 - 512) + ch * 64 + cc)) * N_ + (m0 & 1023) + nseg;
#pragma unroll
      for (int j = 0; j < 4; ++j)
        *reinterpret_cast<i32x4*>(vT + base + j * 8) =
            *reinterpret_cast<const i32x4*>(&Vls[cc][nseg + j * 8]);
    }
  }
}

// ---------------------------------------------------------------------------
// Flash attention + fused output projection — BARRIER-FREE j-loop, SPILL-FREE.
// One wave per head, 16-row i-tile. V + rel read directly from global (vT's
// j-permutation matches the P write layout). No __syncthreads in the j-loop.
// K/V double-buffered (distance 1 tile, L2-resident per-XCD), rel
// double-buffered (8x wave redundancy -> L1/L2 hits after first wave).
// NOTE: no min-waves in launch_bounds — R1's (512,4) made the allocator
// squeeze to 64 VGPR and spill the prefetch buffers (+47MB scratch writes).
// Live-reg budget ~80: 32 K/V, 16 rel, 16 qf/oacc/l_part, ~14 addr.
// ---------------------------------------------------------------------------
__global__ __launch_bounds__(512) void flash_attn(
    const bf16* __restrict__ q, const bf16* __restrict__ kT,
    const bf16* __restrict__ vT, const int* __restrict__ rel,
    const int* __restrict__ rel_len, const float* __restrict__ btab,
    const bf16* __restrict__ Wp_tiled, const float* __restrict__ bias,
    float* __restrict__ out)
{
  __shared__ bf16 Pls[H_][16 * 40]; // wave-private P scratch
  __shared__ float btl[H_][16];     // bias + mask - FMAX
  __shared__ bf16 attL[16][264];    // normalized att rows (all 256 channels)

  int tid = threadIdx.x;
  int h = tid >> 6, lane = tid & 63, quad = lane >> 4, l16 = lane & 15;

  // bijective XCD swizzle (512 blocks = 8 XCDs x 64): XCD k -> batch k.
  int wg = blockIdx.y * 64 + blockIdx.x;
  int swz = (wg & 7) * 64 + (wg >> 3);
  int b = swz >> 6, i0 = (swz & 63) * 16;
  long bN = (long)b * N_;

  int mask_len = (int)((float)rel_len[b] * 0.5f);
  if (tid < 80) {
    int t = tid >> 3, hh = tid & 7;
    btl[hh][t] = btab[t * H_ + hh] + (t > mask_len ? -100.f : 0.f) - FMAX;
  }
  __syncthreads();  // btl ready (only barrier before the tail)

  bf16x8 qf = *reinterpret_cast<const bf16x8*>(
      q + (bN + i0 + l16) * 256 + h * 32 + quad * 8);

  const bf16* kb_ = kT + ((long)(b * H_ + h)) * N_ * 32 + quad * 8;   // + (j+row)*32
  const bf16* vb_ = vT + ((long)b * C_ + h * 32 + l16) * N_ + quad * 8; // + j (+16*N_ row)
  const int*  rb_ = rel + (bN + i0 + quad * 4) * N_ + l16;            // + r*N_ + j (+16)

#define W_(J) ((J) < N_ ? (J) : 0)

#define LDK(K0, K1, V0, V1, J) do {                                          \
    K0 = *reinterpret_cast<const bf16x8*>(kb_ + (long)((J) + l16) * 32);     \
    K1 = *reinterpret_cast<const bf16x8*>(kb_ + (long)((J) + 16 + l16) * 32);\
    V0 = *reinterpret_cast<const bf16x8*>(vb_ + (J));                        \
    V1 = *reinterpret_cast<const bf16x8*>(vb_ + 16 * N_ + (J));              \
  } while (0)

#define LDR(RV, J) do {                                                      \
    _Pragma("unroll")                                                        \
    for (int r = 0; r < 4; ++r) {                                            \
      RV[2 * r]     = rb_[r * N_ + (J)];                                     \
      RV[2 * r + 1] = rb_[r * N_ + (J) + 16];                                \
    }                                                                        \
  } while (0)

#define COMP(K0, K1, V0, V1, RV) do {                                        \
    f32x4 z = {};                                                            \
    f32x4 s0 = __builtin_amdgcn_mfma_f32_16x16x32_bf16(qf, K0, z, 0, 0, 0);  \
    f32x4 s1 = __builtin_amdgcn_mfma_f32_16x16x32_bf16(qf, K1, z, 0, 0, 0);  \
    _Pragma("unroll")                                                        \
    for (int r = 0; r < 4; ++r) {                                            \
      float p0 = __expf(s0[r] + btl[h][RV[2 * r]]);                          \
      float p1 = __expf(s1[r] + btl[h][RV[2 * r + 1]]);                      \
      l_part[r] += p0 + p1;                                                  \
      bf16x2 pp = {(bf16)p0, (bf16)p1}; /* cols 2*l16, 2*l16+1 (j-perm) */   \
      *reinterpret_cast<bf16x2*>(&Pls[h][(quad * 4 + r) * 40 + l16 * 2]) = pp;\
    }                                                                        \
    asm volatile("s_waitcnt lgkmcnt(0)" ::: "memory");                       \
    bf16x8 pf = *reinterpret_cast<const bf16x8*>(&Pls[h][l16 * 40 + quad * 8]);\
    oacc[0] = __builtin_amdgcn_mfma_f32_16x16x32_bf16(pf, V0, oacc[0], 0, 0, 0);\
    oacc[1] = __builtin_amdgcn_mfma_f32_16x16x32_bf16(pf, V1, oacc[1], 0, 0, 0);\
  } while (0)

  f32x4 oacc[2] = {};
  float l_part[4] = {0.f, 0.f, 0.f, 0.f};

  bf16x8 ka0, ka1, vA0, vA1, kb0, kb1, vB0, vB1;
  int ra[8], rb2[8];

  LDK(ka0, ka1, vA0, vA1, 0);
  LDK(kb0, kb1, vB0, vB1, 32);
  LDR(ra, 0); LDR(rb2, 32);

#pragma unroll 1
  for (int j0 = 0; j0 < N_; j0 += 64) {
    COMP(ka0, ka1, vA0, vA1, ra);
    LDK(ka0, ka1, vA0, vA1, W_(j0 + 64));
    LDR(ra, W_(j0 + 64));
    COMP(kb0, kb1, vB0, vB1, rb2);
    LDK(kb0, kb1, vB0, vB1, W_(j0 + 96));
    LDR(rb2, W_(j0 + 96));
  }

  // normalize -> attL (bf16, all channels of this block's 16 rows)
#pragma unroll
  for (int r = 0; r < 4; ++r) {
    float l = l_part[r];
#pragma unroll
    for (int m = 1; m < 16; m <<= 1) l += __shfl_xor(l, m);
    float inv = 1.f / l;
    attL[quad * 4 + r][h * 32 + l16] = (bf16)(oacc[0][r] * inv);
    attL[quad * 4 + r][h * 32 + 16 + l16] = (bf16)(oacc[1][r] * inv);
  }
  __syncthreads();

  // fused projection: wave h computes out[16 rows][h*32 .. h*32+31]
  f32x4 pacc[2] = {};
  const bf16* wp = Wp_tiled + ((h * 32 + l16) * 32 + quad * 8);  // + kt*8192, +512 for ni=1
#pragma unroll
  for (int kt = 0; kt < 8; ++kt) {
    bf16x8 afr = *reinterpret_cast<const bf16x8*>(&attL[l16][kt * 32 + quad * 8]);
    bf16x8 b0 = *reinterpret_cast<const bf16x8*>(wp + kt * 8192);
    bf16x8 b1 = *reinterpret_cast<const bf16x8*>(wp + kt * 8192 + 512);
    pacc[0] = __builtin_amdgcn_mfma_f32_16x16x32_bf16(afr, b0, pacc[0], 0, 0, 0);
    pacc[1] = __builtin_amdgcn_mfma_f32_16x16x32_bf16(afr, b1, pacc[1], 0, 0, 0);
  }
  float bi0 = bias[h * 32 + l16];
  float bi1 = bias[h * 32 + 16 + l16];
#pragma unroll
  for (int r = 0; r < 4; ++r) {
    long rowoff = (bN + i0 + quad * 4 + r) * C_ + h * 32;
    out[rowoff + l16] = pacc[0][r] + bi0;
    out[rowoff + 16 + l16] = pacc[1][r] + bi1;
  }
#undef W_
#undef LDK
#undef LDR
#undef COMP
}

// ---------------------------------------------------------------------------
extern "C" void kernel_launch(void* const* d_in, const int* in_sizes, int n_in,
                              void* d_out, int out_size, void* d_ws, size_t ws_size,
                              hipStream_t stream) {
  const float* X     = (const float*)d_in[0];   // att_embedding [8,1024,256] fp32
  const int*   rel   = (const int*)d_in[1];     // relation_position [8,1024,1024]
  const int*   rlen  = (const int*)d_in[2];     // rel_len [8]
  const float* Wqkv  = (const float*)d_in[3];   // [256,768] fp32
  const float* Wproj = (const float*)d_in[4];   // [256,256] fp32
  const float* bproj = (const float*)d_in[5];   // [256] fp32
  const float* btab  = (const float*)d_in[6];   // [10,8] fp32
  float* out = (float*)d_out;                   // [8,1024,256] fp32

  char* ws = (char*)d_ws;
  bf16* Wq_tiled = (bf16*)ws;                            // 393216 B
  bf16* Wp_tiled = (bf16*)(ws + 393216);                 // 131072 B
  bf16* q  = (bf16*)(ws + 524288);                       // 4 MiB
  bf16* kT = (bf16*)(ws + 524288 + 4194304);             // 4 MiB
  bf16* vT = (bf16*)(ws + 524288 + 2 * 4194304);         // 4 MiB

  prep<<<dim3(1024), 256, 0, stream>>>(Wqkv, Wproj, Wq_tiled, Wp_tiled);
  gemm_qkv<<<dim3(8192 / 128, C3_ / 128), 256, 0, stream>>>(X, Wq_tiled, q, kT, vT);
  flash_attn<<<dim3(N_ / 16, B_), 512, 0, stream>>>(
      q, kT, vT, rel, rlen, btab, Wp_tiled, bproj, out);
}

// Round 3
// 141.731 us; speedup vs baseline: 1.2981x; 1.1324x over previous
//
#include <hip/hip_runtime.h>
#include <hip/hip_bf16.h>

typedef __bf16 bf16;
typedef __bf16 bf16x2 __attribute__((ext_vector_type(2)));
typedef __bf16 bf16x8 __attribute__((ext_vector_type(8)));
typedef float f32x4 __attribute__((ext_vector_type(4)));
typedef int i32x4 __attribute__((ext_vector_type(4)));

#define B_ 8
#define N_ 1024
#define C_ 256
#define H_ 8
#define C3_ 768
#define SCALE 0.17677669529663689f  // 1/sqrt(32), pre-folded into q
#define FMAX 16.0f                  // fixed softmax max, pre-folded into btl

// ws layout:
//   Wq_tiled [8 kt][12 nt][64 n][32 k]   393216 B  @ 0
//   Wp_tiled [8 kt][256 n][32 k]         131072 B  @ 393216
//   q  [8192][256] (pre-scaled by SCALE) 4 MiB     @ 524288
//   kT [b][h][1024 n][32 d]              4 MiB     @ 4718592
//   vT [b][c=h*32+d][1024 n']            4 MiB     @ 8912896
// perm(n within 32): n' = (n&~31) | 2*(n&15) | ((n>>4)&1)

// ---------------------------------------------------------------------------
// prep: transpose + convert weights into tiled bf16 layouts (one-off, tiny).
// ---------------------------------------------------------------------------
__global__ __launch_bounds__(256) void prep(
    const float* __restrict__ Wqkv, const float* __restrict__ Wproj,
    bf16* __restrict__ Wq_tiled, bf16* __restrict__ Wp_tiled)
{
  int bb = blockIdx.x;
  int o = bb * 256 + threadIdx.x;
  if (bb < 768) {
    int kk = o & 31;
    int idx = o >> 5;
    int nr = idx & 63;
    int qq = idx >> 6;            // kt*12 + nt
    int nt = qq % 12, kt = qq / 12;
    int n = nt * 64 + nr, k = kt * 32 + kk;
    Wq_tiled[o] = (bf16)Wqkv[k * C3_ + n];
  } else {
    int p = o - 768 * 256;
    int kk = p & 31;
    int n = (p >> 5) & 255;
    int kt = p >> 13;
    int k = kt * 32 + kk;
    Wp_tiled[p] = (bf16)Wproj[k * C_ + n];
  }
}

// ---------------------------------------------------------------------------
// QKV projection, 128x128 block tile (m93-class): 4 waves, each 64x64 via
// 4x4 f32x4 accumulators -> 16 MFMA per 8 ds_read_b128 per k-step.
// ---------------------------------------------------------------------------
__global__ __launch_bounds__(256) void gemm_qkv(
    const float* __restrict__ A, const bf16* __restrict__ Wq_tiled,
    bf16* __restrict__ q, bf16* __restrict__ kT, bf16* __restrict__ vT)
{
  __shared__ bf16 As[128][40];
  __shared__ bf16 Bts[128][40];   // Bts[n][k]
  __shared__ bf16 Vls[64][136];   // v-epilogue transpose buffer (64ch x 128n)

  int tid = threadIdx.x;
  int wave = tid >> 6, lane = tid & 63, quad = lane >> 4, l16 = lane & 15;
  int m0 = blockIdx.x * 128, n0 = blockIdx.y * 128;
  int msub = (wave & 1) * 64, nsub = (wave >> 1) * 64;

  f32x4 acc[4][4] = {};

  int arow = tid >> 1, akc = (tid & 1) * 16;
  const float* aptr = A + (long)(m0 + arow) * C_ + akc;   // + k0
  int bn = tid >> 1, bkc = (tid & 1) * 16;
  const bf16* bptr = Wq_tiled +
      ((long)(blockIdx.y * 2 + (bn >> 6)) * 2048 + (bn & 63) * 32 + bkc);

  float4 a0 = *reinterpret_cast<const float4*>(aptr);
  float4 a1 = *reinterpret_cast<const float4*>(aptr + 4);
  float4 a2 = *reinterpret_cast<const float4*>(aptr + 8);
  float4 a3 = *reinterpret_cast<const float4*>(aptr + 12);
  i32x4 bv0 = *reinterpret_cast<const i32x4*>(bptr);
  i32x4 bv1 = *reinterpret_cast<const i32x4*>(bptr + 8);

  for (int kt = 0; kt < 8; ++kt) {
    __syncthreads();
    {
      bf16 at[16] = {(bf16)a0.x, (bf16)a0.y, (bf16)a0.z, (bf16)a0.w,
                     (bf16)a1.x, (bf16)a1.y, (bf16)a1.z, (bf16)a1.w,
                     (bf16)a2.x, (bf16)a2.y, (bf16)a2.z, (bf16)a2.w,
                     (bf16)a3.x, (bf16)a3.y, (bf16)a3.z, (bf16)a3.w};
      *reinterpret_cast<bf16x8*>(&As[arow][akc]) = *reinterpret_cast<bf16x8*>(at);
      *reinterpret_cast<bf16x8*>(&As[arow][akc + 8]) = *reinterpret_cast<bf16x8*>(at + 8);
      *reinterpret_cast<i32x4*>(&Bts[bn][bkc]) = bv0;
      *reinterpret_cast<i32x4*>(&Bts[bn][bkc + 8]) = bv1;
    }
    __syncthreads();

    if (kt < 7) {
      int kn = (kt + 1) * 32;
      a0 = *reinterpret_cast<const float4*>(aptr + kn);
      a1 = *reinterpret_cast<const float4*>(aptr + kn + 4);
      a2 = *reinterpret_cast<const float4*>(aptr + kn + 8);
      a3 = *reinterpret_cast<const float4*>(aptr + kn + 12);
      bv0 = *reinterpret_cast<const i32x4*>(bptr + (long)(kt + 1) * 24576);
      bv1 = *reinterpret_cast<const i32x4*>(bptr + (long)(kt + 1) * 24576 + 8);
    }

    bf16x8 af[4], bfr[4];
#pragma unroll
    for (int mi = 0; mi < 4; ++mi)
      af[mi] = *reinterpret_cast<const bf16x8*>(&As[msub + mi * 16 + l16][quad * 8]);
#pragma unroll
    for (int ni = 0; ni < 4; ++ni)
      bfr[ni] = *reinterpret_cast<const bf16x8*>(&Bts[nsub + ni * 16 + l16][quad * 8]);
#pragma unroll
    for (int mi = 0; mi < 4; ++mi)
#pragma unroll
      for (int ni = 0; ni < 4; ++ni)
        acc[mi][ni] = __builtin_amdgcn_mfma_f32_16x16x32_bf16(af[mi], bfr[ni], acc[mi][ni], 0, 0, 0);
  }

  if (n0 < 256) {
#pragma unroll
    for (int mi = 0; mi < 4; ++mi)
#pragma unroll
      for (int ni = 0; ni < 4; ++ni)
#pragma unroll
        for (int r = 0; r < 4; ++r) {
          int row = m0 + msub + mi * 16 + quad * 4 + r;
          int col = n0 + nsub + ni * 16 + l16;
          q[(long)row * 256 + col] = (bf16)(acc[mi][ni][r] * SCALE);
        }
  } else if (n0 < 512) {
#pragma unroll
    for (int mi = 0; mi < 4; ++mi)
#pragma unroll
      for (int ni = 0; ni < 4; ++ni)
#pragma unroll
        for (int r = 0; r < 4; ++r) {
          int row = m0 + msub + mi * 16 + quad * 4 + r;
          int c = n0 + nsub + ni * 16 + l16 - 256;
          int b = row >> 10, n = row & 1023;
          int h = c >> 5, d = c & 31;
          kT[(((long)(b * H_ + h)) * N_ + n) * 32 + d] = (bf16)acc[mi][ni][r];
        }
  } else {
    int b = m0 >> 10;
#pragma unroll
    for (int ch = 0; ch < 2; ++ch) {
      __syncthreads();
      if ((nsub >> 6) == ch) {
#pragma unroll
        for (int mi = 0; mi < 4; ++mi)
#pragma unroll
          for (int ni = 0; ni < 4; ++ni)
#pragma unroll
            for (int r = 0; r < 4; ++r) {
              int cc = ni * 16 + l16;                  // 0..63 within half
              int nn = msub + mi * 16 + quad * 4 + r;  // 0..127
              int np = (nn & 96) | (2 * (nn & 15)) | ((nn >> 4) & 1);
              Vls[cc][np] = (bf16)acc[mi][ni][r];
            }
      }
      __syncthreads();
      int cc = tid >> 2, nseg = (tid & 3) * 32;
      long base = ((long)(b * C_ + (n0 - 512) + ch * 64 + cc)) * N_ + (m0 & 1023) + nseg;
#pragma unroll
      for (int j = 0; j < 4; ++j)
        *reinterpret_cast<i32x4*>(vT + base + j * 8) =
            *reinterpret_cast<const i32x4*>(&Vls[cc][nseg + j * 8]);
    }
  }
}

// ---------------------------------------------------------------------------
// Flash attention (R0 compute body) + fused projection, with DOUBLE-BUFFERED
// cooperative staging and ONE raw s_barrier per j-tile.
// Key change vs the 58.6us baseline: __syncthreads() forces the compiler to
// drain vmcnt(0) at every barrier (m97 analysis), synchronously eating the
// staging-load tail 64x per block. Here: stage regs for tile t+2 are loaded
// during tile t and ds_written at the top of tile t+1 (write-late), and the
// barrier is a raw s_barrier preceded by lgkmcnt(0) ONLY — global loads stay
// in flight across the barrier (~1 full tile of latency cover, counted
// vmcnt inserted by the compiler at the consuming ds_write).
// ---------------------------------------------------------------------------
__global__ __launch_bounds__(512) void flash_attn(
    const bf16* __restrict__ q, const bf16* __restrict__ kT,
    const bf16* __restrict__ vT, const int* __restrict__ rel,
    const int* __restrict__ rel_len, const float* __restrict__ btab,
    const bf16* __restrict__ Wp_tiled, const float* __restrict__ bias,
    float* __restrict__ out)
{
  __shared__ bf16 Vs[2][256][40];      // double-buffered V-tile: [c][j'] (permuted j)
  __shared__ unsigned RelsP[2][4][33]; // double-buffered packed rel: 4 rows/u32
  __shared__ bf16 Pls[H_][16 * 40];    // wave-private P scratch
  __shared__ float btl[H_][16];        // bias + mask - FMAX
  __shared__ bf16 attL[16][264];       // normalized att rows (all 256 channels)

  int tid = threadIdx.x;
  int h = tid >> 6, lane = tid & 63, quad = lane >> 4, l16 = lane & 15;

  // bijective XCD swizzle (512 blocks = 8 XCDs x 64): XCD k -> batch k,
  // so kT/vT/q/rel slices of batch b are L2-resident per XCD (verified R2:
  // FETCH 53.8 -> 23.7 MB).
  int wg = blockIdx.y * 64 + blockIdx.x;
  int swz = (wg & 7) * 64 + (wg >> 3);
  int b = swz >> 6, i0 = (swz & 63) * 16;
  long bN = (long)b * N_;

  int mask_len = (int)((float)rel_len[b] * 0.5f);
  if (tid < 80) {
    int t = tid >> 3, hh = tid & 7;
    btl[hh][t] = btab[t * H_ + hh] + (t > mask_len ? -100.f : 0.f) - FMAX;
  }

  bf16x8 qf = *reinterpret_cast<const bf16x8*>(
      q + (bN + i0 + l16) * 256 + h * 32 + quad * 8);

  const bf16* kbase = kT + ((long)(b * H_ + h)) * N_ * 32 + quad * 8;  // + j*32
  int vrow = tid >> 1, voff = (tid & 1) * 16;
  const bf16* vgp = vT + ((long)b * C_ + vrow) * N_ + voff;            // + j0
  int rg = (tid >> 5) & 3, rcol = tid & 31;
  const int* rgp = rel + (bN + i0 + rg * 4) * N_ + rcol;               // + j0

  f32x4 oacc[2] = {};
  float l_part[4] = {0.f, 0.f, 0.f, 0.f};

  // ---- prologue: tile 0 -> regs -> buf0; tile 1 -> regs; K-frags tile 0.
  bf16x8 vr0 = *reinterpret_cast<const bf16x8*>(vgp);
  bf16x8 vr1 = *reinterpret_cast<const bf16x8*>(vgp + 8);
  int rr0 = 0, rr1 = 0, rr2 = 0, rr3 = 0;
  if (tid < 128) {
    rr0 = rgp[0]; rr1 = rgp[N_]; rr2 = rgp[2 * N_]; rr3 = rgp[3 * N_];
  }
  *reinterpret_cast<bf16x8*>(&Vs[0][vrow][voff]) = vr0;
  *reinterpret_cast<bf16x8*>(&Vs[0][vrow][voff + 8]) = vr1;
  if (tid < 128)
    RelsP[0][rg][rcol] = (unsigned)rr0 | ((unsigned)rr1 << 8) |
                         ((unsigned)rr2 << 16) | ((unsigned)rr3 << 24);
  vr0 = *reinterpret_cast<const bf16x8*>(vgp + 32);
  vr1 = *reinterpret_cast<const bf16x8*>(vgp + 40);
  if (tid < 128) {
    rr0 = rgp[32]; rr1 = rgp[N_ + 32]; rr2 = rgp[2 * N_ + 32]; rr3 = rgp[3 * N_ + 32];
  }
  bf16x8 kf0 = *reinterpret_cast<const bf16x8*>(kbase + (long)l16 * 32);
  bf16x8 kf1 = *reinterpret_cast<const bf16x8*>(kbase + (long)(16 + l16) * 32);
  asm volatile("s_waitcnt lgkmcnt(0)" ::: "memory");
  __builtin_amdgcn_s_barrier();

#define W_(J) ((J) < N_ ? (J) : 0)

// One j-tile: write staged tile t+1 -> buf[NXT]; issue loads tile t+2;
// K-frag prefetch t+1; compute tile t from buf[CUR]; lgkm-only raw barrier.
#define FA_BODY(CUR, NXT, J0) do {                                            \
    *reinterpret_cast<bf16x8*>(&Vs[NXT][vrow][voff]) = vr0;                   \
    *reinterpret_cast<bf16x8*>(&Vs[NXT][vrow][voff + 8]) = vr1;               \
    if (tid < 128)                                                            \
      RelsP[NXT][rg][rcol] = (unsigned)rr0 | ((unsigned)rr1 << 8) |           \
                             ((unsigned)rr2 << 16) | ((unsigned)rr3 << 24);   \
    {                                                                         \
      int j2 = W_((J0) + 64);                                                 \
      vr0 = *reinterpret_cast<const bf16x8*>(vgp + j2);                       \
      vr1 = *reinterpret_cast<const bf16x8*>(vgp + j2 + 8);                   \
      if (tid < 128) {                                                        \
        rr0 = rgp[j2]; rr1 = rgp[N_ + j2];                                    \
        rr2 = rgp[2 * N_ + j2]; rr3 = rgp[3 * N_ + j2];                       \
      }                                                                       \
    }                                                                         \
    int jn = W_((J0) + 32);                                                   \
    bf16x8 kn0 = *reinterpret_cast<const bf16x8*>(kbase + (long)(jn + l16) * 32);      \
    bf16x8 kn1 = *reinterpret_cast<const bf16x8*>(kbase + (long)(jn + 16 + l16) * 32); \
    f32x4 z = {};                                                             \
    f32x4 s0 = __builtin_amdgcn_mfma_f32_16x16x32_bf16(qf, kf0, z, 0, 0, 0);  \
    f32x4 s1 = __builtin_amdgcn_mfma_f32_16x16x32_bf16(qf, kf1, z, 0, 0, 0);  \
    kf0 = kn0; kf1 = kn1;                                                     \
    unsigned w0 = RelsP[CUR][quad][l16];                                      \
    unsigned w1 = RelsP[CUR][quad][16 + l16];                                 \
    _Pragma("unroll")                                                         \
    for (int r = 0; r < 4; ++r) {                                             \
      int il = quad * 4 + r;                                                  \
      int rv0 = (w0 >> (8 * r)) & 255;                                        \
      int rv1 = (w1 >> (8 * r)) & 255;                                        \
      float p0 = __expf(s0[r] + btl[h][rv0]);                                 \
      float p1 = __expf(s1[r] + btl[h][rv1]);                                 \
      l_part[r] += p0 + p1;                                                   \
      bf16x2 pp = {(bf16)p0, (bf16)p1}; /* cols 2*l16, 2*l16+1 (j-perm) */    \
      *reinterpret_cast<bf16x2*>(&Pls[h][il * 40 + l16 * 2]) = pp;            \
    }                                                                         \
    asm volatile("s_waitcnt lgkmcnt(0)" ::: "memory");                        \
    bf16x8 pf = *reinterpret_cast<const bf16x8*>(&Pls[h][l16 * 40 + quad * 8]);        \
    bf16x8 vf0 = *reinterpret_cast<const bf16x8*>(&Vs[CUR][h * 32 + l16][quad * 8]);   \
    bf16x8 vf1 = *reinterpret_cast<const bf16x8*>(&Vs[CUR][h * 32 + 16 + l16][quad * 8]); \
    oacc[0] = __builtin_amdgcn_mfma_f32_16x16x32_bf16(pf, vf0, oacc[0], 0, 0, 0);      \
    oacc[1] = __builtin_amdgcn_mfma_f32_16x16x32_bf16(pf, vf1, oacc[1], 0, 0, 0);      \
    asm volatile("s_waitcnt lgkmcnt(0)" ::: "memory");                        \
    __builtin_amdgcn_s_barrier();                                             \
  } while (0)

#pragma unroll 1
  for (int j0 = 0; j0 < N_; j0 += 64) {
    FA_BODY(0, 1, j0);
    FA_BODY(1, 0, j0 + 32);
  }
#undef FA_BODY
#undef W_

  // normalize -> attL (bf16, all channels of this block's 16 rows)
#pragma unroll
  for (int r = 0; r < 4; ++r) {
    float l = l_part[r];
#pragma unroll
    for (int m = 1; m < 16; m <<= 1) l += __shfl_xor(l, m);
    float inv = 1.f / l;
    attL[quad * 4 + r][h * 32 + l16] = (bf16)(oacc[0][r] * inv);
    attL[quad * 4 + r][h * 32 + 16 + l16] = (bf16)(oacc[1][r] * inv);
  }
  __syncthreads();

  // fused projection: wave h computes out[16 rows][h*32 .. h*32+31]
  f32x4 pacc[2] = {};
  const bf16* wp = Wp_tiled + ((h * 32 + l16) * 32 + quad * 8);  // + kt*8192, +512 for ni=1
#pragma unroll
  for (int kt = 0; kt < 8; ++kt) {
    bf16x8 afr = *reinterpret_cast<const bf16x8*>(&attL[l16][kt * 32 + quad * 8]);
    bf16x8 b0 = *reinterpret_cast<const bf16x8*>(wp + kt * 8192);
    bf16x8 b1 = *reinterpret_cast<const bf16x8*>(wp + kt * 8192 + 512);
    pacc[0] = __builtin_amdgcn_mfma_f32_16x16x32_bf16(afr, b0, pacc[0], 0, 0, 0);
    pacc[1] = __builtin_amdgcn_mfma_f32_16x16x32_bf16(afr, b1, pacc[1], 0, 0, 0);
  }
  float bi0 = bias[h * 32 + l16];
  float bi1 = bias[h * 32 + 16 + l16];
#pragma unroll
  for (int r = 0; r < 4; ++r) {
    long rowoff = (bN + i0 + quad * 4 + r) * C_ + h * 32;
    out[rowoff + l16] = pacc[0][r] + bi0;
    out[rowoff + 16 + l16] = pacc[1][r] + bi1;
  }
}

// ---------------------------------------------------------------------------
extern "C" void kernel_launch(void* const* d_in, const int* in_sizes, int n_in,
                              void* d_out, int out_size, void* d_ws, size_t ws_size,
                              hipStream_t stream) {
  const float* X     = (const float*)d_in[0];   // att_embedding [8,1024,256] fp32
  const int*   rel   = (const int*)d_in[1];     // relation_position [8,1024,1024]
  const int*   rlen  = (const int*)d_in[2];     // rel_len [8]
  const float* Wqkv  = (const float*)d_in[3];   // [256,768] fp32
  const float* Wproj = (const float*)d_in[4];   // [256,256] fp32
  const float* bproj = (const float*)d_in[5];   // [256] fp32
  const float* btab  = (const float*)d_in[6];   // [10,8] fp32
  float* out = (float*)d_out;                   // [8,1024,256] fp32

  char* ws = (char*)d_ws;
  bf16* Wq_tiled = (bf16*)ws;                            // 393216 B
  bf16* Wp_tiled = (bf16*)(ws + 393216);                 // 131072 B
  bf16* q  = (bf16*)(ws + 524288);                       // 4 MiB
  bf16* kT = (bf16*)(ws + 524288 + 4194304);             // 4 MiB
  bf16* vT = (bf16*)(ws + 524288 + 2 * 4194304);         // 4 MiB

  prep<<<dim3(1024), 256, 0, stream>>>(Wqkv, Wproj, Wq_tiled, Wp_tiled);
  gemm_qkv<<<dim3(8192 / 128, C3_ / 128), 256, 0, stream>>>(X, Wq_tiled, q, kT, vT);
  flash_attn<<<dim3(N_ / 16, B_), 512, 0, stream>>>(
      q, kT, vT, rel, rlen, btab, Wp_tiled, bproj, out);
}